// Round 9
// baseline (186.537 us; speedup 1.0000x reference)
//
#include <hip/hip_runtime.h>

#define SB 2048
#define DM 1024
#define N3 3072

typedef short bf16x8 __attribute__((ext_vector_type(8)));
typedef float f32x4 __attribute__((ext_vector_type(4)));
typedef unsigned short u16;

#define MFMA16(a, b, c) __builtin_amdgcn_mfma_f32_16x16x32_bf16(a, b, c, 0, 0, 0)

typedef const __attribute__((address_space(1))) unsigned int* gptr_t;
typedef __attribute__((address_space(3))) unsigned int* lptr_t;

__device__ __forceinline__ u16 f2bf(float x) {
  union { float f; unsigned u; } c; c.f = x;
  unsigned r = c.u + 0x7FFFu + ((c.u >> 16) & 1u);
  return (u16)(r >> 16);
}
__device__ __forceinline__ float bf2f(u16 x) {
  union { unsigned u; float f; } c; c.u = ((unsigned)x) << 16;
  return c.f;
}
__device__ __forceinline__ void glds(const u16* g, u16* l) {
  __builtin_amdgcn_global_load_lds((gptr_t)(const void*)g, (lptr_t)(void*)l, 16, 0, 0);
}

// ---------------- 1) x fp32 -> bf16 ----------------
__global__ void k_cvt_x(const float* __restrict__ x, u16* __restrict__ xb, int n4) {
  int i = blockIdx.x * blockDim.x + threadIdx.x;
  if (i >= n4) return;
  float4 v = ((const float4*)x)[i];
  ushort4 o;
  o.x = f2bf(v.x); o.y = f2bf(v.y); o.z = f2bf(v.z); o.w = f2bf(v.w);
  ((ushort4*)xb)[i] = o;
}

// ---------------- 2) W [1024][3072] f32 -> Wt [3072][1024] bf16 ----------------
__global__ void k_cvt_wt(const float* __restrict__ W, u16* __restrict__ Wt) {
  __shared__ float t[32][33];
  int n0 = blockIdx.x * 32;
  int k0 = blockIdx.y * 32;
  int tx = threadIdx.x & 31, ty = threadIdx.x >> 5;
#pragma unroll
  for (int r = 0; r < 4; ++r)
    t[ty + r * 8][tx] = W[(size_t)(k0 + ty + r * 8) * N3 + n0 + tx];
  __syncthreads();
#pragma unroll
  for (int r = 0; r < 4; ++r)
    Wt[(size_t)(n0 + ty + r * 8) * DM + k0 + tx] = f2bf(t[tx][ty + r * 8]);
}

// ======== shared GEMM core pieces: 128x128 tile, BK=32, 4 waves, 4-deep LDS ring,
// ======== both-sides slot swizzle (0 bank conflicts, HW-proven r8), counted vmcnt.
// LDS per tile-buffer: [128][32] u16, row = 64B = 4 slots of 16B.
// stored slot s at row r holds global k-group ((s - (r>>1)) & 3); read of k-group
// kg at row r uses slot ((kg + (r>>1)) & 3)  ->  2 lanes/bank-slot = free.

// ---------------- 3) QKV GEMM v4 ----------------
__global__ __launch_bounds__(256, 2) void k_gemm(const u16* __restrict__ xb,
                                                 const u16* __restrict__ wt,
                                                 u16* __restrict__ qk,
                                                 u16* __restrict__ vt) {
  __shared__ u16 As[4][128 * 32];
  __shared__ u16 Bs[4][128 * 32];
  int bid = blockIdx.x;
  int mt = bid / 24, nt = bid % 24;
  int m0 = mt * 128, n0 = nt * 128;
  int tid = threadIdx.x, lane = tid & 63, wid = tid >> 6;
  int lr = lane & 15, kg = lane >> 4;
  int wm = (wid >> 1) * 64, wn = (wid & 1) * 64;
  int r2 = tid >> 2, seg = tid & 3;
  int scol = ((seg - (r2 >> 1)) & 3) * 8;     // inverse swizzle on global col
  const u16* a0 = xb + (size_t)(m0 + r2) * 1024 + scol;
  const u16* a1 = xb + (size_t)(m0 + 64 + r2) * 1024 + scol;
  const u16* b0 = wt + (size_t)(n0 + r2) * 1024 + scol;
  const u16* b1 = wt + (size_t)(n0 + 64 + r2) * 1024 + scol;

#define STAGE(kt) do { int _b = (kt) & 3; int _o = (kt) * 32;            \
    glds(a0 + _o, &As[_b][tid * 8]);                                     \
    glds(a1 + _o, &As[_b][2048 + tid * 8]);                              \
    glds(b0 + _o, &Bs[_b][tid * 8]);                                     \
    glds(b1 + _o, &Bs[_b][2048 + tid * 8]); } while (0)

  f32x4 acc[4][4] = {};
  STAGE(0); STAGE(1);
  asm volatile("s_waitcnt vmcnt(4)" ::: "memory");
  __builtin_amdgcn_s_barrier();
  for (int t = 0; t < 32; ++t) {
    if (t < 30) STAGE(t + 2);
    int buf = t & 3;
    bf16x8 af[4], bff[4];
#pragma unroll
    for (int i = 0; i < 4; ++i) {
      int row = wm + i * 16 + lr;
      af[i] = *(const bf16x8*)&As[buf][row * 32 + ((kg + (row >> 1)) & 3) * 8];
    }
#pragma unroll
    for (int j = 0; j < 4; ++j) {
      int row = wn + j * 16 + lr;
      bff[j] = *(const bf16x8*)&Bs[buf][row * 32 + ((kg + (row >> 1)) & 3) * 8];
    }
    __builtin_amdgcn_s_setprio(1);
#pragma unroll
    for (int i = 0; i < 4; ++i)
#pragma unroll
      for (int j = 0; j < 4; ++j)
        acc[i][j] = MFMA16(af[i], bff[j], acc[i][j]);
    __builtin_amdgcn_s_setprio(0);
    if (t < 31) {
      if (t < 30) asm volatile("s_waitcnt vmcnt(4)" ::: "memory");
      else        asm volatile("s_waitcnt vmcnt(0)" ::: "memory");
      __builtin_amdgcn_s_barrier();
    }
  }
#undef STAGE

  if (n0 < 2048) {
#pragma unroll
    for (int i = 0; i < 4; ++i)
#pragma unroll
      for (int j = 0; j < 4; ++j)
#pragma unroll
        for (int r = 0; r < 4; ++r)
          qk[(size_t)(m0 + wm + i * 16 + kg * 4 + r) * 2048 + n0 + wn + j * 16 + lr] = f2bf(acc[i][j][r]);
  } else {
#pragma unroll
    for (int i = 0; i < 4; ++i)
#pragma unroll
      for (int j = 0; j < 4; ++j)
#pragma unroll
        for (int r = 0; r < 4; ++r) {
          int m = m0 + wm + i * 16 + kg * 4 + r;
          int d = n0 + wn + j * 16 + lr - 2048;
          vt[(size_t)((m >> 11) * DM + d) * SB + (m & 2047)] = f2bf(acc[i][j][r]);
        }
  }
}

// ---------------- 4) S = Q K^T / 32, block-triangular (kt >= qt), bf16 ----------------
__global__ __launch_bounds__(256, 2) void k_qkt(const u16* __restrict__ qk,
                                                u16* __restrict__ S) {
  __shared__ u16 As[4][128 * 32];
  __shared__ u16 Bs[4][128 * 32];
  int bid = blockIdx.x;
  int b = bid & 3;
  int pi = bid >> 2;                 // 0..135 -> (qt, kt) with kt >= qt
  int qt = 0;
  while (true) { int cnt = 16 - qt; if (pi < cnt) break; pi -= cnt; ++qt; }
  int kt = qt + pi;
  int m0 = qt * 128, n0 = kt * 128;
  int tid = threadIdx.x, lane = tid & 63, wid = tid >> 6;
  int lr = lane & 15, kg = lane >> 4;
  int wm = (wid >> 1) * 64, wn = (wid & 1) * 64;
  int r2 = tid >> 2, seg = tid & 3;
  int scol = ((seg - (r2 >> 1)) & 3) * 8;
  const u16* Qb = qk + (size_t)(b * SB) * 2048;
  const u16* a0 = Qb + (size_t)(m0 + r2) * 2048 + scol;
  const u16* a1 = Qb + (size_t)(m0 + 64 + r2) * 2048 + scol;
  const u16* b0 = Qb + (size_t)(n0 + r2) * 2048 + 1024 + scol;
  const u16* b1 = Qb + (size_t)(n0 + 64 + r2) * 2048 + 1024 + scol;

#define STAGE(kt_) do { int _b = (kt_) & 3; int _o = (kt_) * 32;         \
    glds(a0 + _o, &As[_b][tid * 8]);                                     \
    glds(a1 + _o, &As[_b][2048 + tid * 8]);                              \
    glds(b0 + _o, &Bs[_b][tid * 8]);                                     \
    glds(b1 + _o, &Bs[_b][2048 + tid * 8]); } while (0)

  f32x4 acc[4][4] = {};
  STAGE(0); STAGE(1);
  asm volatile("s_waitcnt vmcnt(4)" ::: "memory");
  __builtin_amdgcn_s_barrier();
  for (int t = 0; t < 32; ++t) {
    if (t < 30) STAGE(t + 2);
    int buf = t & 3;
    bf16x8 af[4], bff[4];
#pragma unroll
    for (int i = 0; i < 4; ++i) {
      int row = wm + i * 16 + lr;
      af[i] = *(const bf16x8*)&As[buf][row * 32 + ((kg + (row >> 1)) & 3) * 8];
    }
#pragma unroll
    for (int j = 0; j < 4; ++j) {
      int row = wn + j * 16 + lr;
      bff[j] = *(const bf16x8*)&Bs[buf][row * 32 + ((kg + (row >> 1)) & 3) * 8];
    }
    __builtin_amdgcn_s_setprio(1);
#pragma unroll
    for (int i = 0; i < 4; ++i)
#pragma unroll
      for (int j = 0; j < 4; ++j)
        acc[i][j] = MFMA16(af[i], bff[j], acc[i][j]);
    __builtin_amdgcn_s_setprio(0);
    if (t < 31) {
      if (t < 30) asm volatile("s_waitcnt vmcnt(4)" ::: "memory");
      else        asm volatile("s_waitcnt vmcnt(0)" ::: "memory");
      __builtin_amdgcn_s_barrier();
    }
  }
#undef STAGE

  u16* Sb = S + (size_t)(b * SB) * 2048;
#pragma unroll
  for (int i = 0; i < 4; ++i)
#pragma unroll
    for (int j = 0; j < 4; ++j)
#pragma unroll
      for (int r = 0; r < 4; ++r) {
        int q = m0 + wm + i * 16 + kg * 4 + r;
        int k = n0 + wn + j * 16 + lr;
        float v = acc[i][j][r] * 0.03125f;
        if (k < q) v = -1e30f;         // keep key >= query (anti-causal)
        Sb[(size_t)q * 2048 + k] = f2bf(v);
      }
}

// ---------------- 5) row softmax in-place on S (valid range k >= qt*128) ----------------
__global__ void k_sm(u16* __restrict__ S) {
  __shared__ float rmax[4], rsum[4];
  int row = blockIdx.x;              // b*2048 + q
  int q = row & 2047;
  int k0 = (q >> 7) << 7;
  int len = 2048 - k0;               // multiple of 128
  int tid = threadIdx.x;
  u16* rp = S + (size_t)row * 2048 + k0;
  int nv = len >> 3;
  bool act = tid < nv;
  float v[8];
  float mx = -1e30f;
  if (act) {
    bf16x8 x = *(const bf16x8*)(rp + tid * 8);
#pragma unroll
    for (int j = 0; j < 8; ++j) { v[j] = bf2f((u16)x[j]); mx = fmaxf(mx, v[j]); }
  }
#pragma unroll
  for (int off = 32; off; off >>= 1) mx = fmaxf(mx, __shfl_xor(mx, off, 64));
  int wv = tid >> 6;
  if ((tid & 63) == 0) rmax[wv] = mx;
  __syncthreads();
  mx = fmaxf(fmaxf(rmax[0], rmax[1]), fmaxf(rmax[2], rmax[3]));
  float sum = 0.f;
  if (act) {
#pragma unroll
    for (int j = 0; j < 8; ++j) { v[j] = __expf(v[j] - mx); sum += v[j]; }
  }
#pragma unroll
  for (int off = 32; off; off >>= 1) sum += __shfl_xor(sum, off, 64);
  if ((tid & 63) == 0) rsum[wv] = sum;
  __syncthreads();
  float inv = 1.f / ((rsum[0] + rsum[1]) + (rsum[2] + rsum[3]));
  if (act) {
    bf16x8 o;
#pragma unroll
    for (int j = 0; j < 8; ++j) o[j] = (short)f2bf(v[j] * inv);
    *(bf16x8*)(rp + tid * 8) = o;
  }
}

// ---------------- 6) O = P V, block-triangular variable-K, f32 out ----------------
__global__ __launch_bounds__(256, 2) void k_pv(const u16* __restrict__ P,
                                               const u16* __restrict__ vt,
                                               float* __restrict__ out) {
  __shared__ u16 As[4][128 * 32];
  __shared__ u16 Bs[4][128 * 32];
  int bid = blockIdx.x;
  int qt = bid >> 5;                 // heavy-first (qt=0 has longest K-loop)
  int rem = bid & 31;
  int dt = rem >> 2;
  int b = rem & 3;
  int m0 = qt * 128, n0 = dt * 128;
  int nkt = (2048 - m0) >> 5;        // K-tiles of 32, >= 4 always
  int tid = threadIdx.x, lane = tid & 63, wid = tid >> 6;
  int lr = lane & 15, kg = lane >> 4;
  int wm = (wid >> 1) * 64, wn = (wid & 1) * 64;
  int r2 = tid >> 2, seg = tid & 3;
  int scol = ((seg - (r2 >> 1)) & 3) * 8;
  const u16* Pb = P + (size_t)(b * SB) * 2048;
  const u16* Vb = vt + (size_t)(b * DM) * 2048;
  const u16* a0 = Pb + (size_t)(m0 + r2) * 2048 + m0 + scol;
  const u16* a1 = Pb + (size_t)(m0 + 64 + r2) * 2048 + m0 + scol;
  const u16* b0 = Vb + (size_t)(n0 + r2) * 2048 + m0 + scol;
  const u16* b1 = Vb + (size_t)(n0 + 64 + r2) * 2048 + m0 + scol;

#define STAGE(kt_) do { int _b = (kt_) & 3; int _o = (kt_) * 32;         \
    glds(a0 + _o, &As[_b][tid * 8]);                                     \
    glds(a1 + _o, &As[_b][2048 + tid * 8]);                              \
    glds(b0 + _o, &Bs[_b][tid * 8]);                                     \
    glds(b1 + _o, &Bs[_b][2048 + tid * 8]); } while (0)

  f32x4 acc[4][4] = {};
  STAGE(0); STAGE(1);
  asm volatile("s_waitcnt vmcnt(4)" ::: "memory");
  __builtin_amdgcn_s_barrier();
  for (int t = 0; t < nkt; ++t) {
    if (t + 2 < nkt) STAGE(t + 2);
    int buf = t & 3;
    bf16x8 af[4], bff[4];
#pragma unroll
    for (int i = 0; i < 4; ++i) {
      int row = wm + i * 16 + lr;
      af[i] = *(const bf16x8*)&As[buf][row * 32 + ((kg + (row >> 1)) & 3) * 8];
    }
#pragma unroll
    for (int j = 0; j < 4; ++j) {
      int row = wn + j * 16 + lr;
      bff[j] = *(const bf16x8*)&Bs[buf][row * 32 + ((kg + (row >> 1)) & 3) * 8];
    }
    __builtin_amdgcn_s_setprio(1);
#pragma unroll
    for (int i = 0; i < 4; ++i)
#pragma unroll
      for (int j = 0; j < 4; ++j)
        acc[i][j] = MFMA16(af[i], bff[j], acc[i][j]);
    __builtin_amdgcn_s_setprio(0);
    if (t + 1 < nkt) {
      if (t + 2 < nkt) asm volatile("s_waitcnt vmcnt(4)" ::: "memory");
      else             asm volatile("s_waitcnt vmcnt(0)" ::: "memory");
      __builtin_amdgcn_s_barrier();
    }
  }
#undef STAGE

#pragma unroll
  for (int i = 0; i < 4; ++i)
#pragma unroll
    for (int j = 0; j < 4; ++j)
#pragma unroll
      for (int r = 0; r < 4; ++r)
        out[(size_t)(b * SB + m0 + wm + i * 16 + kg * 4 + r) * DM + n0 + wn + j * 16 + lr] = acc[i][j][r];
}

extern "C" void kernel_launch(void* const* d_in, const int* in_sizes, int n_in,
                              void* d_out, int out_size, void* d_ws, size_t ws_size,
                              hipStream_t stream) {
  const float* x = (const float*)d_in[0];
  const float* W = (const float*)d_in[1];
  float* out = (float*)d_out;
  char* ws = (char*)d_ws;
  // layout (80 MB total):
  u16* qk = (u16*)(ws);                  // 32 MB : [8192][2048] bf16 (Q | K)
  u16* vt = (u16*)(ws + 33554432);       // 16 MB : [4][1024][2048] bf16 (V^T)
  u16* xb = (u16*)(ws + 50331648);       // 16 MB : x bf16 (dead after k_gemm)
  u16* wt = (u16*)(ws + 67108864);       //  6 MB : W^T bf16 (dead after k_gemm)
  u16* S  = (u16*)(ws + 50331648);       // 32 MB : scores/P bf16, reuses xb+wt region

  k_cvt_x<<<8192, 256, 0, stream>>>(x, xb, 2097152);
  dim3 gw(96, 32);
  k_cvt_wt<<<gw, 256, 0, stream>>>(W, wt);
  k_gemm<<<1536, 256, 0, stream>>>(xb, wt, qk, vt);
  k_qkt<<<544, 256, 0, stream>>>(qk, S);
  k_sm<<<8192, 256, 0, stream>>>(S);
  k_pv<<<512, 256, 0, stream>>>(S, vt, out);
}

// Round 10
// 171.914 us; speedup vs baseline: 1.0851x; 1.0851x over previous
//
#include <hip/hip_runtime.h>

#define SB 2048
#define DM 1024
#define N3 3072

typedef short bf16x8 __attribute__((ext_vector_type(8)));
typedef float f32x4 __attribute__((ext_vector_type(4)));
typedef unsigned short u16;

#define MFMA16(a, b, c) __builtin_amdgcn_mfma_f32_16x16x32_bf16(a, b, c, 0, 0, 0)

typedef const __attribute__((address_space(1))) unsigned int* gptr_t;
typedef __attribute__((address_space(3))) unsigned int* lptr_t;

__device__ __forceinline__ u16 f2bf(float x) {
  union { float f; unsigned u; } c; c.f = x;
  unsigned r = c.u + 0x7FFFu + ((c.u >> 16) & 1u);
  return (u16)(r >> 16);
}
__device__ __forceinline__ float bf2f(u16 x) {
  union { unsigned u; float f; } c; c.u = ((unsigned)x) << 16;
  return c.f;
}
__device__ __forceinline__ void glds(const u16* g, u16* l) {
  __builtin_amdgcn_global_load_lds((gptr_t)(const void*)g, (lptr_t)(void*)l, 16, 0, 0);
}

// ---------------- 1) x fp32 -> bf16 ----------------
__global__ void k_cvt_x(const float* __restrict__ x, u16* __restrict__ xb, int n4) {
  int i = blockIdx.x * blockDim.x + threadIdx.x;
  if (i >= n4) return;
  float4 v = ((const float4*)x)[i];
  ushort4 o;
  o.x = f2bf(v.x); o.y = f2bf(v.y); o.z = f2bf(v.z); o.w = f2bf(v.w);
  ((ushort4*)xb)[i] = o;
}

// ---------------- 2) W [1024][3072] f32 -> Wt [3072][1024] bf16 ----------------
__global__ void k_cvt_wt(const float* __restrict__ W, u16* __restrict__ Wt) {
  __shared__ float t[32][33];
  int n0 = blockIdx.x * 32;
  int k0 = blockIdx.y * 32;
  int tx = threadIdx.x & 31, ty = threadIdx.x >> 5;
#pragma unroll
  for (int r = 0; r < 4; ++r)
    t[ty + r * 8][tx] = W[(size_t)(k0 + ty + r * 8) * N3 + n0 + tx];
  __syncthreads();
#pragma unroll
  for (int r = 0; r < 4; ++r)
    Wt[(size_t)(n0 + ty + r * 8) * DM + k0 + tx] = f2bf(t[tx][ty + r * 8]);
}

// ---------------- 3) QKV GEMM v5: 256x256 tile, per-phase interleave ----------------
// BK=32, ring-4 LDS (128 KB), 8 waves (2M x 4N), per-wave 128x64 out (acc[8][4]).
// Per K-tile: 2 phases, each {ds_read frags | issue 1 half stage | barrier |
// lgkmcnt(0)+sched_barrier | setprio(1) 16 MFMA setprio(0) | barrier}; vmcnt(4)
// once per K-tile (counted, never 0 in steady state). Stage target buf[(t+2)&3]
// was last read at t-2 (>=2 barriers ago) -> WAR-free by construction.
// Slot swizzle (both sides) -> 0 bank conflicts (HW-proven r8/r9).
__global__ __launch_bounds__(512, 1) void k_gemm(const u16* __restrict__ xb,
                                                 const u16* __restrict__ wt,
                                                 u16* __restrict__ qk,
                                                 u16* __restrict__ vt) {
  __shared__ u16 As[4][256 * 32];   // 64 KB
  __shared__ u16 Bs[4][256 * 32];   // 64 KB
  int bid = blockIdx.x;
  int swz = (bid & 7) * 48 + (bid >> 3);     // bijective XCD swizzle (384 = 8*48)
  int mt = swz / 12, nt = swz % 12;          // consecutive-in-XCD share mt (A-panel L2 reuse)
  int m0 = mt * 256, n0 = nt * 256;
  int tid = threadIdx.x, lane = tid & 63, wid = tid >> 6;
  int lr = lane & 15, kg = lane >> 4;
  int wm = (wid >> 2) * 128, wn = (wid & 3) * 64;
  int r2 = tid >> 2, seg = tid & 3;
  int scol = ((seg - (r2 >> 1)) & 3) * 8;    // inverse slot swizzle on global col
  const u16* a0 = xb + (size_t)(m0 + r2) * 1024 + scol;
  const u16* a1 = xb + (size_t)(m0 + 128 + r2) * 1024 + scol;
  const u16* b0 = wt + (size_t)(n0 + r2) * 1024 + scol;
  const u16* b1 = wt + (size_t)(n0 + 128 + r2) * 1024 + scol;

#define STAGE_A(kt) do { int _b = (kt) & 3; int _o = (kt) * 32;          \
    glds(a0 + _o, &As[_b][tid * 8]);                                     \
    glds(a1 + _o, &As[_b][4096 + tid * 8]); } while (0)
#define STAGE_B(kt) do { int _b = (kt) & 3; int _o = (kt) * 32;          \
    glds(b0 + _o, &Bs[_b][tid * 8]);                                     \
    glds(b1 + _o, &Bs[_b][4096 + tid * 8]); } while (0)

  f32x4 acc[8][4] = {};
  STAGE_A(0); STAGE_B(0);
  STAGE_A(1); STAGE_B(1);
  asm volatile("s_waitcnt vmcnt(4)" ::: "memory");   // K-tile 0 landed
  __builtin_amdgcn_s_barrier();

  for (int t = 0; t < 32; ++t) {
    int buf = t & 3;
    // ---- phase 0: M-frags 0-3 ----
    bf16x8 bff[4], af[4];
#pragma unroll
    for (int j = 0; j < 4; ++j) {
      int row = wn + j * 16 + lr;
      bff[j] = *(const bf16x8*)&Bs[buf][row * 32 + ((kg + (row >> 1)) & 3) * 8];
    }
#pragma unroll
    for (int i = 0; i < 4; ++i) {
      int row = wm + i * 16 + lr;
      af[i] = *(const bf16x8*)&As[buf][row * 32 + ((kg + (row >> 1)) & 3) * 8];
    }
    if (t <= 29) STAGE_A(t + 2);
    __builtin_amdgcn_s_barrier();
    asm volatile("s_waitcnt lgkmcnt(0)" ::: "memory");
    __builtin_amdgcn_sched_barrier(0);
    __builtin_amdgcn_s_setprio(1);
#pragma unroll
    for (int i = 0; i < 4; ++i)
#pragma unroll
      for (int j = 0; j < 4; ++j)
        acc[i][j] = MFMA16(af[i], bff[j], acc[i][j]);
    __builtin_amdgcn_s_setprio(0);
    __builtin_amdgcn_s_barrier();
    // ---- phase 1: M-frags 4-7 (bff reused) ----
#pragma unroll
    for (int i = 0; i < 4; ++i) {
      int row = wm + 64 + i * 16 + lr;
      af[i] = *(const bf16x8*)&As[buf][row * 32 + ((kg + (row >> 1)) & 3) * 8];
    }
    if (t <= 29) STAGE_B(t + 2);
    __builtin_amdgcn_s_barrier();
    asm volatile("s_waitcnt lgkmcnt(0)" ::: "memory");
    __builtin_amdgcn_sched_barrier(0);
    __builtin_amdgcn_s_setprio(1);
#pragma unroll
    for (int i = 0; i < 4; ++i)
#pragma unroll
      for (int j = 0; j < 4; ++j)
        acc[4 + i][j] = MFMA16(af[i], bff[j], acc[4 + i][j]);
    __builtin_amdgcn_s_setprio(0);
    if (t <= 29)      asm volatile("s_waitcnt vmcnt(4)" ::: "memory");  // K-tile t+1 landed
    else if (t == 30) asm volatile("s_waitcnt vmcnt(0)" ::: "memory");
    __builtin_amdgcn_s_barrier();
  }
#undef STAGE_A
#undef STAGE_B

  if (n0 < 2048) {
#pragma unroll
    for (int i = 0; i < 8; ++i)
#pragma unroll
      for (int j = 0; j < 4; ++j)
#pragma unroll
        for (int r = 0; r < 4; ++r)
          qk[(size_t)(m0 + wm + i * 16 + kg * 4 + r) * 2048 + n0 + wn + j * 16 + lr] = f2bf(acc[i][j][r]);
  } else {
#pragma unroll
    for (int i = 0; i < 8; ++i)
#pragma unroll
      for (int j = 0; j < 4; ++j)
#pragma unroll
        for (int r = 0; r < 4; ++r) {
          int m = m0 + wm + i * 16 + kg * 4 + r;
          int d = n0 + wn + j * 16 + lr - 2048;
          vt[(size_t)((m >> 11) * DM + d) * SB + (m & 2047)] = f2bf(acc[i][j][r]);
        }
  }
}

// ---------------- 4) S = Q K^T / 32, block-triangular (kt >= qt), bf16 ----------------
// (r7 structure: 2-buf parity, __syncthreads drains — proven fast + replay-stable)
__global__ __launch_bounds__(256, 2) void k_qkt(const u16* __restrict__ qk,
                                                u16* __restrict__ S) {
  __shared__ u16 As[2][128 * 32];
  __shared__ u16 Bs[2][128 * 32];
  int bid = blockIdx.x;
  int b = bid & 3;
  int pi = bid >> 2;                 // 0..135 -> (qt, kt) with kt >= qt
  int qt = 0;
  while (true) { int cnt = 16 - qt; if (pi < cnt) break; pi -= cnt; ++qt; }
  int kt = qt + pi;
  int m0 = qt * 128, n0 = kt * 128;
  int tid = threadIdx.x, lane = tid & 63, wid = tid >> 6;
  int lr = lane & 15, lg = lane >> 4;
  int wm = (wid >> 1) * 64, wn = (wid & 1) * 64;
  int ca = lane >> 2;
  int cb = (lane & 3) * 8;
  const u16* Qb = qk + (size_t)(b * SB) * 2048;
  f32x4 acc[4][4] = {};
  int p = 0;
  for (int kk = 0; kk < 1024; kk += 32) {
#pragma unroll
    for (int j = 0; j < 2; ++j) {
      int chunk = wid * 2 + j;
      const u16* ga = Qb + (size_t)(m0 + chunk * 16 + ca) * 2048 + kk + cb;          // Q
      const u16* gb = Qb + (size_t)(n0 + chunk * 16 + ca) * 2048 + 1024 + kk + cb;   // K
      glds(ga, &As[p][chunk * 512]);
      glds(gb, &Bs[p][chunk * 512]);
    }
    __syncthreads();
    bf16x8 af[4], bff[4];
#pragma unroll
    for (int i = 0; i < 4; ++i) af[i] = *(const bf16x8*)&As[p][(wm + i * 16 + lr) * 32 + lg * 8];
#pragma unroll
    for (int j = 0; j < 4; ++j) bff[j] = *(const bf16x8*)&Bs[p][(wn + j * 16 + lr) * 32 + lg * 8];
#pragma unroll
    for (int i = 0; i < 4; ++i)
#pragma unroll
      for (int j = 0; j < 4; ++j)
        acc[i][j] = MFMA16(af[i], bff[j], acc[i][j]);
    __syncthreads();
    p ^= 1;
  }
  u16* Sb = S + (size_t)(b * SB) * 2048;
#pragma unroll
  for (int i = 0; i < 4; ++i)
#pragma unroll
    for (int j = 0; j < 4; ++j)
#pragma unroll
      for (int r = 0; r < 4; ++r) {
        int q = m0 + wm + i * 16 + lg * 4 + r;
        int k = n0 + wn + j * 16 + lr;
        float v = acc[i][j][r] * 0.03125f;
        if (k < q) v = -1e30f;         // keep key >= query (anti-causal)
        Sb[(size_t)q * 2048 + k] = f2bf(v);
      }
}

// ---------------- 5) row softmax in-place on S (valid range k >= qt*128) ----------------
__global__ void k_sm(u16* __restrict__ S) {
  __shared__ float rmax[4], rsum[4];
  int row = blockIdx.x;              // b*2048 + q
  int q = row & 2047;
  int k0 = (q >> 7) << 7;
  int len = 2048 - k0;               // multiple of 128
  int tid = threadIdx.x;
  u16* rp = S + (size_t)row * 2048 + k0;
  int nv = len >> 3;
  bool act = tid < nv;
  float v[8];
  float mx = -1e30f;
  if (act) {
    bf16x8 x = *(const bf16x8*)(rp + tid * 8);
#pragma unroll
    for (int j = 0; j < 8; ++j) { v[j] = bf2f((u16)x[j]); mx = fmaxf(mx, v[j]); }
  }
#pragma unroll
  for (int off = 32; off; off >>= 1) mx = fmaxf(mx, __shfl_xor(mx, off, 64));
  int wv = tid >> 6;
  if ((tid & 63) == 0) rmax[wv] = mx;
  __syncthreads();
  mx = fmaxf(fmaxf(rmax[0], rmax[1]), fmaxf(rmax[2], rmax[3]));
  float sum = 0.f;
  if (act) {
#pragma unroll
    for (int j = 0; j < 8; ++j) { v[j] = __expf(v[j] - mx); sum += v[j]; }
  }
#pragma unroll
  for (int off = 32; off; off >>= 1) sum += __shfl_xor(sum, off, 64);
  if ((tid & 63) == 0) rsum[wv] = sum;
  __syncthreads();
  float inv = 1.f / ((rsum[0] + rsum[1]) + (rsum[2] + rsum[3]));
  if (act) {
    bf16x8 o;
#pragma unroll
    for (int j = 0; j < 8; ++j) o[j] = (short)f2bf(v[j] * inv);
    *(bf16x8*)(rp + tid * 8) = o;
  }
}

// ---------------- 6) O = P V, block-triangular variable-K, f32 out ----------------
// (r7 structure)
__global__ __launch_bounds__(256, 2) void k_pv(const u16* __restrict__ P,
                                               const u16* __restrict__ vt,
                                               float* __restrict__ out) {
  __shared__ u16 As[2][128 * 32];
  __shared__ u16 Bs[2][128 * 32];
  int bid = blockIdx.x;
  int qt = bid >> 5;                 // heavy-first (qt=0 has longest K-loop)
  int rem = bid & 31;
  int dt = rem >> 2;
  int b = rem & 3;
  int m0 = qt * 128, n0 = dt * 128;
  int tid = threadIdx.x, lane = tid & 63, wid = tid >> 6;
  int lr = lane & 15, lg = lane >> 4;
  int wm = (wid >> 1) * 64, wn = (wid & 1) * 64;
  int ca = lane >> 2;
  int cb = (lane & 3) * 8;
  const u16* Pb = P + (size_t)(b * SB) * 2048;
  const u16* Vb = vt + (size_t)(b * DM) * 2048;
  f32x4 acc[4][4] = {};
  int p = 0;
  for (int kk = m0; kk < 2048; kk += 32) {
#pragma unroll
    for (int j = 0; j < 2; ++j) {
      int chunk = wid * 2 + j;
      const u16* ga = Pb + (size_t)(m0 + chunk * 16 + ca) * 2048 + kk + cb;
      const u16* gb = Vb + (size_t)(n0 + chunk * 16 + ca) * 2048 + kk + cb;
      glds(ga, &As[p][chunk * 512]);
      glds(gb, &Bs[p][chunk * 512]);
    }
    __syncthreads();
    bf16x8 af[4], bff[4];
#pragma unroll
    for (int i = 0; i < 4; ++i) af[i] = *(const bf16x8*)&As[p][(wm + i * 16 + lr) * 32 + lg * 8];
#pragma unroll
    for (int j = 0; j < 4; ++j) bff[j] = *(const bf16x8*)&Bs[p][(wn + j * 16 + lr) * 32 + lg * 8];
#pragma unroll
    for (int i = 0; i < 4; ++i)
#pragma unroll
      for (int j = 0; j < 4; ++j)
        acc[i][j] = MFMA16(af[i], bff[j], acc[i][j]);
    __syncthreads();
    p ^= 1;
  }
#pragma unroll
  for (int i = 0; i < 4; ++i)
#pragma unroll
    for (int j = 0; j < 4; ++j)
#pragma unroll
      for (int r = 0; r < 4; ++r)
        out[(size_t)(b * SB + m0 + wm + i * 16 + lg * 4 + r) * DM + n0 + wn + j * 16 + lr] = acc[i][j][r];
}

extern "C" void kernel_launch(void* const* d_in, const int* in_sizes, int n_in,
                              void* d_out, int out_size, void* d_ws, size_t ws_size,
                              hipStream_t stream) {
  const float* x = (const float*)d_in[0];
  const float* W = (const float*)d_in[1];
  float* out = (float*)d_out;
  char* ws = (char*)d_ws;
  // layout (80 MB total):
  u16* qk = (u16*)(ws);                  // 32 MB : [8192][2048] bf16 (Q | K)
  u16* vt = (u16*)(ws + 33554432);       // 16 MB : [4][1024][2048] bf16 (V^T)
  u16* xb = (u16*)(ws + 50331648);       // 16 MB : x bf16 (dead after k_gemm)
  u16* wt = (u16*)(ws + 67108864);       //  6 MB : W^T bf16 (dead after k_gemm)
  u16* S  = (u16*)(ws + 50331648);       // 32 MB : scores/P bf16, reuses xb+wt region

  k_cvt_x<<<8192, 256, 0, stream>>>(x, xb, 2097152);
  dim3 gw(96, 32);
  k_cvt_wt<<<gw, 256, 0, stream>>>(W, wt);
  k_gemm<<<384, 512, 0, stream>>>(xb, wt, qk, vt);
  k_qkt<<<544, 256, 0, stream>>>(qk, S);
  k_sm<<<8192, 256, 0, stream>>>(S);
  k_pv<<<512, 256, 0, stream>>>(S, vt, out);
}

// Round 11
// 165.953 us; speedup vs baseline: 1.1240x; 1.0359x over previous
//
#include <hip/hip_runtime.h>

#define SB 2048
#define DM 1024
#define N3 3072

typedef short bf16x8 __attribute__((ext_vector_type(8)));
typedef float f32x4 __attribute__((ext_vector_type(4)));
typedef unsigned short u16;

#define MFMA16(a, b, c) __builtin_amdgcn_mfma_f32_16x16x32_bf16(a, b, c, 0, 0, 0)

typedef const __attribute__((address_space(1))) unsigned int* gptr_t;
typedef __attribute__((address_space(3))) unsigned int* lptr_t;

__device__ __forceinline__ u16 f2bf(float x) {
  union { float f; unsigned u; } c; c.f = x;
  unsigned r = c.u + 0x7FFFu + ((c.u >> 16) & 1u);
  return (u16)(r >> 16);
}
__device__ __forceinline__ float bf2f(u16 x) {
  union { unsigned u; float f; } c; c.u = ((unsigned)x) << 16;
  return c.f;
}
__device__ __forceinline__ void glds(const u16* g, u16* l) {
  __builtin_amdgcn_global_load_lds((gptr_t)(const void*)g, (lptr_t)(void*)l, 16, 0, 0);
}

// slot swizzle (HW-proven 0-conflict in r8/r9/r10):
// store: thread covering row r, seg s stages global col ((s-(r>>1))&3)*8 at linear slot s
// read:  k-group kg at row r found at slot ((kg+(r>>1))&3)

// ---------------- 1) x fp32 -> bf16 ----------------
__global__ void k_cvt_x(const float* __restrict__ x, u16* __restrict__ xb, int n4) {
  int i = blockIdx.x * blockDim.x + threadIdx.x;
  if (i >= n4) return;
  float4 v = ((const float4*)x)[i];
  ushort4 o;
  o.x = f2bf(v.x); o.y = f2bf(v.y); o.z = f2bf(v.z); o.w = f2bf(v.w);
  ((ushort4*)xb)[i] = o;
}

// ---------------- 2) W [1024][3072] f32 -> Wt [3072][1024] bf16 ----------------
__global__ void k_cvt_wt(const float* __restrict__ W, u16* __restrict__ Wt) {
  __shared__ float t[32][33];
  int n0 = blockIdx.x * 32;
  int k0 = blockIdx.y * 32;
  int tx = threadIdx.x & 31, ty = threadIdx.x >> 5;
#pragma unroll
  for (int r = 0; r < 4; ++r)
    t[ty + r * 8][tx] = W[(size_t)(k0 + ty + r * 8) * N3 + n0 + tx];
  __syncthreads();
#pragma unroll
  for (int r = 0; r < 4; ++r)
    Wt[(size_t)(n0 + ty + r * 8) * DM + k0 + tx] = f2bf(t[tx][ty + r * 8]);
}

// ---------------- 3) QKV GEMM (r7 structure + slot swizzle) ----------------
__global__ __launch_bounds__(256, 2) void k_gemm(const u16* __restrict__ xb,
                                                 const u16* __restrict__ wt,
                                                 u16* __restrict__ qk,
                                                 u16* __restrict__ vt) {
  __shared__ u16 As[2][128 * 32];
  __shared__ u16 Bs[2][128 * 32];
  int bid = blockIdx.x;
  int mt = bid / 24, nt = bid % 24;
  int m0 = mt * 128, n0 = nt * 128;
  int tid = threadIdx.x, lane = tid & 63, wid = tid >> 6;
  int lr = lane & 15, lg = lane >> 4;
  int wm = (wid >> 1) * 64, wn = (wid & 1) * 64;
  int ca = lane >> 2;                       // row within 16-row staging chunk
  int seg = lane & 3;                       // 16B slot within row
  f32x4 acc[4][4] = {};
  int p = 0;
  for (int kk = 0; kk < 1024; kk += 32) {
#pragma unroll
    for (int j = 0; j < 2; ++j) {
      int chunk = wid * 2 + j;
      int row = chunk * 16 + ca;
      int scol = ((seg - (row >> 1)) & 3) * 8;   // inverse swizzle on global col
      const u16* ga = xb + (size_t)(m0 + row) * 1024 + kk + scol;
      const u16* gb = wt + (size_t)(n0 + row) * 1024 + kk + scol;
      glds(ga, &As[p][chunk * 512]);
      glds(gb, &Bs[p][chunk * 512]);
    }
    __syncthreads();
    bf16x8 af[4], bff[4];
#pragma unroll
    for (int i = 0; i < 4; ++i) {
      int row = wm + i * 16 + lr;
      af[i] = *(const bf16x8*)&As[p][row * 32 + ((lg + (row >> 1)) & 3) * 8];
    }
#pragma unroll
    for (int j = 0; j < 4; ++j) {
      int row = wn + j * 16 + lr;
      bff[j] = *(const bf16x8*)&Bs[p][row * 32 + ((lg + (row >> 1)) & 3) * 8];
    }
#pragma unroll
    for (int i = 0; i < 4; ++i)
#pragma unroll
      for (int j = 0; j < 4; ++j)
        acc[i][j] = MFMA16(af[i], bff[j], acc[i][j]);
    __syncthreads();
    p ^= 1;
  }
  if (n0 < 2048) {
#pragma unroll
    for (int i = 0; i < 4; ++i)
#pragma unroll
      for (int j = 0; j < 4; ++j)
#pragma unroll
        for (int r = 0; r < 4; ++r)
          qk[(size_t)(m0 + wm + i * 16 + lg * 4 + r) * 2048 + n0 + wn + j * 16 + lr] = f2bf(acc[i][j][r]);
  } else {
#pragma unroll
    for (int i = 0; i < 4; ++i)
#pragma unroll
      for (int j = 0; j < 4; ++j)
#pragma unroll
        for (int r = 0; r < 4; ++r) {
          int m = m0 + wm + i * 16 + lg * 4 + r;
          int d = n0 + wn + j * 16 + lr - 2048;
          vt[(size_t)((m >> 11) * DM + d) * SB + (m & 2047)] = f2bf(acc[i][j][r]);
        }
  }
}

// ---------------- 4) S = Q K^T / 32, block-triangular (kt >= qt), bf16 ----------------
__global__ __launch_bounds__(256, 2) void k_qkt(const u16* __restrict__ qk,
                                                u16* __restrict__ S) {
  __shared__ u16 As[2][128 * 32];
  __shared__ u16 Bs[2][128 * 32];
  int bid = blockIdx.x;
  int b = bid & 3;
  int pi = bid >> 2;                 // 0..135 -> (qt, kt) with kt >= qt
  int qt = 0;
  while (true) { int cnt = 16 - qt; if (pi < cnt) break; pi -= cnt; ++qt; }
  int kt = qt + pi;
  int m0 = qt * 128, n0 = kt * 128;
  int tid = threadIdx.x, lane = tid & 63, wid = tid >> 6;
  int lr = lane & 15, lg = lane >> 4;
  int wm = (wid >> 1) * 64, wn = (wid & 1) * 64;
  int ca = lane >> 2;
  int seg = lane & 3;
  const u16* Qb = qk + (size_t)(b * SB) * 2048;
  f32x4 acc[4][4] = {};
  int p = 0;
  for (int kk = 0; kk < 1024; kk += 32) {
#pragma unroll
    for (int j = 0; j < 2; ++j) {
      int chunk = wid * 2 + j;
      int row = chunk * 16 + ca;
      int scol = ((seg - (row >> 1)) & 3) * 8;
      const u16* ga = Qb + (size_t)(m0 + row) * 2048 + kk + scol;          // Q
      const u16* gb = Qb + (size_t)(n0 + row) * 2048 + 1024 + kk + scol;   // K
      glds(ga, &As[p][chunk * 512]);
      glds(gb, &Bs[p][chunk * 512]);
    }
    __syncthreads();
    bf16x8 af[4], bff[4];
#pragma unroll
    for (int i = 0; i < 4; ++i) {
      int row = wm + i * 16 + lr;
      af[i] = *(const bf16x8*)&As[p][row * 32 + ((lg + (row >> 1)) & 3) * 8];
    }
#pragma unroll
    for (int j = 0; j < 4; ++j) {
      int row = wn + j * 16 + lr;
      bff[j] = *(const bf16x8*)&Bs[p][row * 32 + ((lg + (row >> 1)) & 3) * 8];
    }
#pragma unroll
    for (int i = 0; i < 4; ++i)
#pragma unroll
      for (int j = 0; j < 4; ++j)
        acc[i][j] = MFMA16(af[i], bff[j], acc[i][j]);
    __syncthreads();
    p ^= 1;
  }
  u16* Sb = S + (size_t)(b * SB) * 2048;
#pragma unroll
  for (int i = 0; i < 4; ++i)
#pragma unroll
    for (int j = 0; j < 4; ++j)
#pragma unroll
      for (int r = 0; r < 4; ++r) {
        int q = m0 + wm + i * 16 + lg * 4 + r;
        int k = n0 + wn + j * 16 + lr;
        float v = acc[i][j][r] * 0.03125f;
        if (k < q) v = -1e30f;         // keep key >= query (anti-causal)
        Sb[(size_t)q * 2048 + k] = f2bf(v);
      }
}

// ---------------- 5) row softmax in-place on S (valid range k >= qt*128) ----------------
__global__ void k_sm(u16* __restrict__ S) {
  __shared__ float rmax[4], rsum[4];
  int row = blockIdx.x;              // b*2048 + q
  int q = row & 2047;
  int k0 = (q >> 7) << 7;
  int len = 2048 - k0;               // multiple of 128
  int tid = threadIdx.x;
  u16* rp = S + (size_t)row * 2048 + k0;
  int nv = len >> 3;
  bool act = tid < nv;
  float v[8];
  float mx = -1e30f;
  if (act) {
    bf16x8 x = *(const bf16x8*)(rp + tid * 8);
#pragma unroll
    for (int j = 0; j < 8; ++j) { v[j] = bf2f((u16)x[j]); mx = fmaxf(mx, v[j]); }
  }
#pragma unroll
  for (int off = 32; off; off >>= 1) mx = fmaxf(mx, __shfl_xor(mx, off, 64));
  int wv = tid >> 6;
  if ((tid & 63) == 0) rmax[wv] = mx;
  __syncthreads();
  mx = fmaxf(fmaxf(rmax[0], rmax[1]), fmaxf(rmax[2], rmax[3]));
  float sum = 0.f;
  if (act) {
#pragma unroll
    for (int j = 0; j < 8; ++j) { v[j] = __expf(v[j] - mx); sum += v[j]; }
  }
#pragma unroll
  for (int off = 32; off; off >>= 1) sum += __shfl_xor(sum, off, 64);
  if ((tid & 63) == 0) rsum[wv] = sum;
  __syncthreads();
  float inv = 1.f / ((rsum[0] + rsum[1]) + (rsum[2] + rsum[3]));
  if (act) {
    bf16x8 o;
#pragma unroll
    for (int j = 0; j < 8; ++j) o[j] = (short)f2bf(v[j] * inv);
    *(bf16x8*)(rp + tid * 8) = o;
  }
}

// ---------------- 6) O = P V, block-triangular variable-K, f32 out ----------------
__global__ __launch_bounds__(256, 2) void k_pv(const u16* __restrict__ P,
                                               const u16* __restrict__ vt,
                                               float* __restrict__ out) {
  __shared__ u16 As[2][128 * 32];
  __shared__ u16 Bs[2][128 * 32];
  int bid = blockIdx.x;
  int qt = bid >> 5;                 // heavy-first (qt=0 has longest K-loop)
  int rem = bid & 31;
  int dt = rem >> 2;
  int b = rem & 3;
  int m0 = qt * 128, n0 = dt * 128;
  int tid = threadIdx.x, lane = tid & 63, wid = tid >> 6;
  int lr = lane & 15, lg = lane >> 4;
  int wm = (wid >> 1) * 64, wn = (wid & 1) * 64;
  int ca = lane >> 2;
  int seg = lane & 3;
  const u16* Pb = P + (size_t)(b * SB) * 2048;
  const u16* Vb = vt + (size_t)(b * DM) * 2048;
  f32x4 acc[4][4] = {};
  int p = 0;
  for (int kk = m0; kk < 2048; kk += 32) {
#pragma unroll
    for (int j = 0; j < 2; ++j) {
      int chunk = wid * 2 + j;
      int row = chunk * 16 + ca;
      int scol = ((seg - (row >> 1)) & 3) * 8;
      const u16* ga = Pb + (size_t)(m0 + row) * 2048 + kk + scol;
      const u16* gb = Vb + (size_t)(n0 + row) * 2048 + kk + scol;
      glds(ga, &As[p][chunk * 512]);
      glds(gb, &Bs[p][chunk * 512]);
    }
    __syncthreads();
    bf16x8 af[4], bff[4];
#pragma unroll
    for (int i = 0; i < 4; ++i) {
      int row = wm + i * 16 + lr;
      af[i] = *(const bf16x8*)&As[p][row * 32 + ((lg + (row >> 1)) & 3) * 8];
    }
#pragma unroll
    for (int j = 0; j < 4; ++j) {
      int row = wn + j * 16 + lr;
      bff[j] = *(const bf16x8*)&Bs[p][row * 32 + ((lg + (row >> 1)) & 3) * 8];
    }
#pragma unroll
    for (int i = 0; i < 4; ++i)
#pragma unroll
      for (int j = 0; j < 4; ++j)
        acc[i][j] = MFMA16(af[i], bff[j], acc[i][j]);
    __syncthreads();
    p ^= 1;
  }
#pragma unroll
  for (int i = 0; i < 4; ++i)
#pragma unroll
    for (int j = 0; j < 4; ++j)
#pragma unroll
      for (int r = 0; r < 4; ++r)
        out[(size_t)(b * SB + m0 + wm + i * 16 + lg * 4 + r) * DM + n0 + wn + j * 16 + lr] = acc[i][j][r];
}

extern "C" void kernel_launch(void* const* d_in, const int* in_sizes, int n_in,
                              void* d_out, int out_size, void* d_ws, size_t ws_size,
                              hipStream_t stream) {
  const float* x = (const float*)d_in[0];
  const float* W = (const float*)d_in[1];
  float* out = (float*)d_out;
  char* ws = (char*)d_ws;
  // layout (80 MB total):
  u16* qk = (u16*)(ws);                  // 32 MB : [8192][2048] bf16 (Q | K)
  u16* vt = (u16*)(ws + 33554432);       // 16 MB : [4][1024][2048] bf16 (V^T)
  u16* xb = (u16*)(ws + 50331648);       // 16 MB : x bf16 (dead after k_gemm)
  u16* wt = (u16*)(ws + 67108864);       //  6 MB : W^T bf16 (dead after k_gemm)
  u16* S  = (u16*)(ws + 50331648);       // 32 MB : scores/P bf16, reuses xb+wt region

  k_cvt_x<<<8192, 256, 0, stream>>>(x, xb, 2097152);
  dim3 gw(96, 32);
  k_cvt_wt<<<gw, 256, 0, stream>>>(W, wt);
  k_gemm<<<1536, 256, 0, stream>>>(xb, wt, qk, vt);
  k_qkt<<<544, 256, 0, stream>>>(qk, S);
  k_sm<<<8192, 256, 0, stream>>>(S);
  k_pv<<<512, 256, 0, stream>>>(S, vt, out);
}